// Round 9
// baseline (131.632 us; speedup 1.0000x reference)
//
#include <hip/hip_runtime.h>
#include <hip/hip_cooperative_groups.h>

namespace cg = cooperative_groups;

// Problem constants
#define BATCH 16384
#define ZDIM  256
#define NCLS  1000
#define NPAD  1024

typedef float f32x4 __attribute__((ext_vector_type(4)));

// Workspace layout (bytes). xq/cq fp8 e4m3, fragment-ordered (see R8).
#define WS_XQ   0
#define WS_CQ   4194304
#define WS_XSQ  4456448
#define WS_CSQ  4521984
#define WS_PART 4526080

#define GLOAD_LDS(gp, lp)                                                     \
    __builtin_amdgcn_global_load_lds(                                         \
        (__attribute__((address_space(1))) const void*)(gp),                  \
        (__attribute__((address_space(3))) void*)(lp), 16, 0, 0)

template <bool W>
__device__ __forceinline__ int pk2fp8(float a, float b, int old) {
    return __builtin_amdgcn_cvt_pk_fp8_f32(a, b, old, W);
}

// ONE cooperative kernel: phase 1 converts fp32 -> fp8 fragment-ordered +
// row norms; grid.sync(); phase 2 = R8's 256x256 fp8 MFMA GEMM + fused
// distance/mask/reduce. 256 blocks x 512 threads = exactly 1 block/CU.
// Round-9 rationale: R5 (gemm~43us) and R8 (8x less traffic) produced the
// SAME total -> either gemm is mysteriously pinned at ~40us or ~35us is
// inter-dispatch gap. Fusing to one dispatch decides it and fixes (b).
__global__ __launch_bounds__(512, 2) void fused(
        const float* __restrict__ x,
        const float* __restrict__ centers,
        const int* __restrict__ labels,
        char* __restrict__ xq,
        char* __restrict__ cq,
        float* __restrict__ xsq,
        float* __restrict__ csq,
        float* __restrict__ part) {
    __shared__ char smem[65536];

    const int tid  = threadIdx.x;
    const int lane = tid & 63;
    const int wid  = tid >> 6;
    const int b    = blockIdx.x;
    const int bm   = b & 63;       // 0..63 (same bm -> same XCD, %8 dispatch)
    const int bn   = b >> 6;       // 0..3
    const int lr   = lane & 15;
    const int quad = lane >> 4;

    // ---- Phase 1: prep. Block b converts the A-mtiles its bm-group reads
    // (producer and consumer share an XCD). Blocks 0..63: one ctile each.
    if (wid < 4) {
        const int mt = bm * 16 + bn * 4 + wid;               // 0..1023, 1:1
        const float* src = x + (size_t)(mt * 16 + lr) * ZDIM + quad * 8;
        float s = 0.0f;
        #pragma unroll
        for (int kt = 0; kt < 8; ++kt) {
            const float4 a = *(const float4*)(src + kt * 32);
            const float4 c = *(const float4*)(src + kt * 32 + 4);
            s += a.x*a.x + a.y*a.y + a.z*a.z + a.w*a.w
               + c.x*c.x + c.y*c.y + c.z*c.z + c.w*c.w;
            int lo = pk2fp8<false>(a.x, a.y, 0); lo = pk2fp8<true>(a.z, a.w, lo);
            int hi = pk2fp8<false>(c.x, c.y, 0); hi = pk2fp8<true>(c.z, c.w, hi);
            int2 v; v.x = lo; v.y = hi;
            *(int2*)(xq + ((size_t)(mt * 8 + kt) * 64 + lane) * 8) = v;
        }
        s += __shfl_xor(s, 16);
        s += __shfl_xor(s, 32);
        if (lane < 16) xsq[mt * 16 + lane] = s;
    } else if (wid == 4 && bn == 0) {
        const int ct  = bm;                                   // 0..63
        const int row = ct * 16 + lr;
        const bool ok = (row < NCLS);
        const float* src = centers + (size_t)row * ZDIM + quad * 8;
        float s = 0.0f;
        #pragma unroll
        for (int kt = 0; kt < 8; ++kt) {
            float4 a = {0,0,0,0}, c = {0,0,0,0};
            if (ok) {
                a = *(const float4*)(src + kt * 32);
                c = *(const float4*)(src + kt * 32 + 4);
            }
            s += a.x*a.x + a.y*a.y + a.z*a.z + a.w*a.w
               + c.x*c.x + c.y*c.y + c.z*c.z + c.w*c.w;
            int lo = pk2fp8<false>(a.x, a.y, 0); lo = pk2fp8<true>(a.z, a.w, lo);
            int hi = pk2fp8<false>(c.x, c.y, 0); hi = pk2fp8<true>(c.z, c.w, hi);
            int2 v; v.x = lo; v.y = hi;
            *(int2*)(cq + ((size_t)(ct * 8 + kt) * 64 + lane) * 8) = v;
        }
        s += __shfl_xor(s, 16);
        s += __shfl_xor(s, 32);
        if (lane < 16) csq[ct * 16 + lane] = s;   // pad rows got zeros
    }

    cg::this_grid().sync();

    // ---- Phase 2: R8's fp8 GEMM + epilogue, verbatim.
    const int m0 = bm * 256;
    const int n0 = bn * 256;
    const int wr = wid & 3;              // wave row group: 64 rows
    const int wc = wid >> 2;             // wave col group: 128 cols

    f32x4 acc_r[4][8];
    #pragma unroll
    for (int i = 0; i < 4; ++i)
        #pragma unroll
        for (int j = 0; j < 8; ++j) {
            f32x4 z = {0.0f, 0.0f, 0.0f, 0.0f};
            acc_r[i][j] = z;
        }

    const long long* AL = (const long long*)smem;
    const long long* BL = (const long long*)(smem + 32768);

    #pragma unroll
    for (int h = 0; h < 2; ++h) {
        #pragma unroll
        for (int it = 0; it < 4; ++it) {
            const int c = it * 512 + tid;              // 0..2047 (16B chunks)
            const int mtile = c >> 7, kt4 = (c >> 5) & 3, pair = c & 31;
            const char* g = xq + (size_t)((bm * 16 + mtile) * 8 + h * 4 + kt4) * 512
                               + pair * 16;
            GLOAD_LDS(g, smem + c * 16);
        }
        #pragma unroll
        for (int it = 0; it < 4; ++it) {
            const int c = it * 512 + tid;
            const int ctile = c >> 7, kt4 = (c >> 5) & 3, pair = c & 31;
            const char* g = cq + (size_t)((bn * 16 + ctile) * 8 + h * 4 + kt4) * 512
                               + pair * 16;
            GLOAD_LDS(g, smem + 32768 + c * 16);
        }
        __syncthreads();

        #pragma unroll
        for (int kt4 = 0; kt4 < 4; ++kt4) {
            long long af[4], bf[8];
            #pragma unroll
            for (int mi = 0; mi < 4; ++mi)
                af[mi] = AL[((wr * 4 + mi) * 4 + kt4) * 64 + lane];
            #pragma unroll
            for (int nj = 0; nj < 8; ++nj)
                bf[nj] = BL[((wc * 8 + nj) * 4 + kt4) * 64 + lane];
            #pragma unroll
            for (int mi = 0; mi < 4; ++mi)
                #pragma unroll
                for (int nj = 0; nj < 8; ++nj)
                    acc_r[mi][nj] = __builtin_amdgcn_mfma_f32_16x16x32_fp8_fp8(
                        af[mi], bf[nj], acc_r[mi][nj], 0, 0, 0);
        }
        __syncthreads();
    }

    // Epilogue scalars into dead LDS
    float* xsq_s = (float*)smem;             // 256 f32
    float* csq_s = (float*)(smem + 1024);    // 256 f32
    int*   lab_s = (int*)(smem + 2048);      // 256 i32
    float* wsum  = (float*)(smem + 3072);    // 8 f32
    if (tid < 256) {
        xsq_s[tid] = xsq[m0 + tid];
        lab_s[tid] = labels[m0 + tid];
    } else {
        const int t = tid - 256;
        csq_s[t] = csq[n0 + t];
    }
    __syncthreads();

    // dist -> sqrt -> clamp -> mask (label & pad) -> sum
    // C/D layout (16x16): col = lane&15, row = (lane>>4)*4 + reg  [m89/m91]
    float sum = 0.0f;
    #pragma unroll
    for (int nj = 0; nj < 8; ++nj) {
        const int col_l = wc * 128 + nj * 16 + lr;
        const int col_g = n0 + col_l;
        const float cs = csq_s[col_l];
        const bool colok = (col_g < NCLS);
        #pragma unroll
        for (int mi = 0; mi < 4; ++mi) {
            #pragma unroll
            for (int r = 0; r < 4; ++r) {
                const int row_l = wr * 64 + mi * 16 + quad * 4 + r;
                float dist = xsq_s[row_l] + cs - 2.0f * acc_r[mi][nj][r];
                float d = sqrtf(fmaxf(dist, 0.0f));
                d = fminf(fmaxf(d, 1e-8f), 1e8f);
                if (colok && (lab_s[row_l] != col_g)) sum += d;
            }
        }
    }

    #pragma unroll
    for (int off = 32; off; off >>= 1) sum += __shfl_down(sum, off);
    if (lane == 0) wsum[wid] = sum;
    __syncthreads();
    if (tid == 0) {
        float t = 0.0f;
        #pragma unroll
        for (int w = 0; w < 8; ++w) t += wsum[w];
        part[blockIdx.x] = t;
    }
}

// Reduce 256 partials -> loss (kernel boundary gives cross-XCD visibility).
__global__ void finalize(const float* __restrict__ part, float* __restrict__ out) {
    const int tid  = threadIdx.x;
    const int lane = tid & 63;
    const int wid  = tid >> 6;
    __shared__ float wsum[4];
    float s = part[tid];
    #pragma unroll
    for (int off = 32; off; off >>= 1) s += __shfl_down(s, off);
    if (lane == 0) wsum[wid] = s;
    __syncthreads();
    if (tid == 0)
        out[0] = (wsum[0] + wsum[1] + wsum[2] + wsum[3]) * (1.0f / (16384.0f * 999.0f));
}

extern "C" void kernel_launch(void* const* d_in, const int* in_sizes, int n_in,
                              void* d_out, int out_size, void* d_ws, size_t ws_size,
                              hipStream_t stream) {
    const float* x       = (const float*)d_in[0];
    const float* centers = (const float*)d_in[1];
    const int*   labels  = (const int*)d_in[2];
    float*       out     = (float*)d_out;

    char* ws = (char*)d_ws;
    char*  xq   = ws + WS_XQ;
    char*  cq   = ws + WS_CQ;
    float* xsq  = (float*)(ws + WS_XSQ);
    float* csq  = (float*)(ws + WS_CSQ);
    float* part = (float*)(ws + WS_PART);

    void* args[] = {(void*)&x, (void*)&centers, (void*)&labels,
                    (void*)&xq, (void*)&cq, (void*)&xsq, (void*)&csq,
                    (void*)&part};
    hipLaunchCooperativeKernel((const void*)fused, dim3(256), dim3(512),
                               args, 0, stream);
    finalize<<<1, 256, 0, stream>>>(part, out);
}

// Round 10
// 91.019 us; speedup vs baseline: 1.4462x; 1.4462x over previous
//
#include <hip/hip_runtime.h>

// Problem constants
#define BATCH 16384
#define ZDIM  256
#define NCLS  1000
#define NPAD  1024

typedef __bf16 bf16x8 __attribute__((ext_vector_type(8)));
typedef float  f32x4  __attribute__((ext_vector_type(4)));

// ===== Session findings (R0-R9) =====
// - This kernel (R5 structure) is the empirical best: 93.46 us total.
// - Total = harness ws-poison fill (268 MB @ 6.2 TB/s = 43-45 us, untouchable)
//   + input restore (~3 us) + pipeline (~45 us) + gaps.
// - The pipeline's ~45 us is NOT pipe-bound: across 7 structural variants
//   (traffic 268->33 MB, barriers 8->0, atomics 1024->0, 1-4 dispatches,
//   bf16/fp8, coop fusion) duration stayed 42-58 us. Counters only become
//   self-consistent at ~500-600 MHz effective core clock: the memory-bound
//   poison fill + ms-scale replay gaps keep DPM parked, so short compute
//   dispatches run in a low-clock window (~constant ~45 us device-state cost).
// - Proven real wins along the way: XCD-aware bm-swizzle (FETCH 33.8->12 MB),
//   no device-scope atomics/fences in hot kernel (R3: 1024 same-line RMWs +
//   __threadfence L2-writebacks serialized ~50us), plain-store partials +
//   separate finalize, fragment-preswizzled operands (zero LDS, zero
//   bank conflicts, zero K-loop barriers).
//
// Workspace layout (bytes). xb/cb PRE-SWIZZLED in MFMA fragment order:
// chunk((tile,kt,lane)) = ((tile*8 + kt)*64 + lane) * 16B holding
// src[tile*16 + (lane&15)][kt*32 + (lane>>4)*8 .. +8] as bf16, so each
// fragment load is one lane-linear global_load_dwordx4.
#define WS_XB   0
#define WS_CB   8388608
#define WS_XSQ  8912896
#define WS_CSQ  8978432
#define WS_PART 8982528

__device__ __forceinline__ unsigned short f2bf(float f) {
    union { float f; unsigned int u; } v; v.f = f;
    unsigned int u = v.u;
    unsigned int r = (u + 0x7fffu + ((u >> 16) & 1u)) >> 16;   // RNE
    return (unsigned short)r;
}

// Fused prep. Blocks [0,256): x -> swizzled xb + xsq (wave per 16-row tile).
// Blocks [256,272): centers -> swizzled cb (zero-padded to 1024) + csq.
__global__ void prep(const float* __restrict__ x,
                     const float* __restrict__ centers,
                     unsigned short* __restrict__ xb,
                     unsigned short* __restrict__ cb,
                     float* __restrict__ xsq,
                     float* __restrict__ csq) {
    const int wid  = threadIdx.x >> 6;
    const int lane = threadIdx.x & 63;
    const int lr   = lane & 15;
    const int quad = lane >> 4;

    if (blockIdx.x < 256) {
        const int mt = blockIdx.x * 4 + wid;                 // 0..1023
        const float* src = x + (size_t)(mt * 16 + lr) * ZDIM + quad * 8;
        float s = 0.0f;
        #pragma unroll
        for (int kt = 0; kt < 8; ++kt) {
            const float4 a = *(const float4*)(src + kt * 32);
            const float4 b = *(const float4*)(src + kt * 32 + 4);
            s += a.x*a.x + a.y*a.y + a.z*a.z + a.w*a.w
               + b.x*b.x + b.y*b.y + b.z*b.z + b.w*b.w;
            unsigned short* dst = xb + ((size_t)(mt * 8 + kt) * 64 + lane) * 8;
            ushort4 lo, hi;
            lo.x = f2bf(a.x); lo.y = f2bf(a.y); lo.z = f2bf(a.z); lo.w = f2bf(a.w);
            hi.x = f2bf(b.x); hi.y = f2bf(b.y); hi.z = f2bf(b.z); hi.w = f2bf(b.w);
            *(ushort4*)dst       = lo;
            *(ushort4*)(dst + 4) = hi;
        }
        s += __shfl_xor(s, 16);
        s += __shfl_xor(s, 32);
        if (lane < 16) xsq[mt * 16 + lane] = s;
    } else {
        const int ct  = (blockIdx.x - 256) * 4 + wid;        // 0..63
        const int row = ct * 16 + lr;
        const bool ok = (row < NCLS);
        const float* src = centers + (size_t)row * ZDIM + quad * 8;
        float s = 0.0f;
        #pragma unroll
        for (int kt = 0; kt < 8; ++kt) {
            float4 a = {0,0,0,0}, b = {0,0,0,0};
            if (ok) {
                a = *(const float4*)(src + kt * 32);
                b = *(const float4*)(src + kt * 32 + 4);
            }
            s += a.x*a.x + a.y*a.y + a.z*a.z + a.w*a.w
               + b.x*b.x + b.y*b.y + b.z*b.z + b.w*b.w;
            unsigned short* dst = cb + ((size_t)(ct * 8 + kt) * 64 + lane) * 8;
            ushort4 lo, hi;
            lo.x = f2bf(a.x); lo.y = f2bf(a.y); lo.z = f2bf(a.z); lo.w = f2bf(a.w);
            hi.x = f2bf(b.x); hi.y = f2bf(b.y); hi.z = f2bf(b.z); hi.w = f2bf(b.w);
            *(ushort4*)dst       = lo;
            *(ushort4*)(dst + 4) = hi;
        }
        s += __shfl_xor(s, 16);
        s += __shfl_xor(s, 32);
        if (lane < 16) csq[ct * 16 + lane] = s;   // pad rows accumulated zeros
    }
}

// Fused GEMM + distance + mask + block reduce.
// XCD-aware: bm = blockIdx%128 -> all 8 blocks sharing an A-tile land on the
// same XCD (round-robin %8 dispatch). 128x128 per block, 2x2 waves of 64x64,
// 16x16x32 bf16 MFMA, fragments loaded directly from pre-swizzled global
// (L2-hot, no LDS staging, no K-loop barriers), partial sum via plain store.
__global__ __launch_bounds__(256, 3) void gemm_loss(
        const unsigned short* __restrict__ xb,
        const unsigned short* __restrict__ cb,
        const float* __restrict__ xsq,
        const float* __restrict__ csq,
        const int* __restrict__ labels,
        float* __restrict__ part) {
    __shared__ float xsq_s[128];
    __shared__ float csq_s[128];
    __shared__ int   lab_s[128];
    __shared__ float wsum[4];

    const int tid  = threadIdx.x;
    const int lane = tid & 63;
    const int wid  = tid >> 6;
    const int bm   = blockIdx.x & 127;     // 0..127  (same bm -> same XCD)
    const int bn   = blockIdx.x >> 7;      // 0..7
    const int m0   = bm * 128;
    const int n0   = bn * 128;

    if (tid < 128) {
        xsq_s[tid] = xsq[m0 + tid];
        lab_s[tid] = labels[m0 + tid];
    } else {
        const int t = tid - 128;
        csq_s[t] = csq[n0 + t];
    }

    const int wm = wid & 1;      // wave row (0/1) -> 64 rows
    const int wn = wid >> 1;     // wave col (0/1) -> 64 cols

    f32x4 acc_r[4][4];
    #pragma unroll
    for (int i = 0; i < 4; ++i)
        #pragma unroll
        for (int j = 0; j < 4; ++j) {
            f32x4 z = {0.0f, 0.0f, 0.0f, 0.0f};
            acc_r[i][j] = z;
        }

    const int mtb = bm * 8 + wm * 4;       // first of 4 A 16-row tiles
    const int ctb = bn * 8 + wn * 4;       // first of 4 B 16-col tiles
    const bf16x8* __restrict__ A = (const bf16x8*)xb;
    const bf16x8* __restrict__ B = (const bf16x8*)cb;

    #pragma unroll
    for (int kt = 0; kt < 8; ++kt) {
        bf16x8 af[4], bfr[4];
        #pragma unroll
        for (int i = 0; i < 4; ++i)
            af[i] = A[(size_t)((mtb + i) * 8 + kt) * 64 + lane];
        #pragma unroll
        for (int j = 0; j < 4; ++j)
            bfr[j] = B[(size_t)((ctb + j) * 8 + kt) * 64 + lane];
        #pragma unroll
        for (int i = 0; i < 4; ++i)
            #pragma unroll
            for (int j = 0; j < 4; ++j)
                acc_r[i][j] = __builtin_amdgcn_mfma_f32_16x16x32_bf16(
                    af[i], bfr[j], acc_r[i][j], 0, 0, 0);
    }

    __syncthreads();   // staging of xsq_s/csq_s/lab_s visible before epilogue

    // Epilogue: dist -> sqrt -> clamp -> mask (label & pad) -> sum
    // C/D layout (16x16): col = lane&15, row = (lane>>4)*4 + reg  [m89/m91]
    const int quad = lane >> 4;
    const int lr   = lane & 15;
    float sum = 0.0f;
    #pragma unroll
    for (int j = 0; j < 4; ++j) {
        const int col_l = wn * 64 + j * 16 + lr;
        const int col_g = n0 + col_l;
        const float cs = csq_s[col_l];
        const bool colok = (col_g < NCLS);
        #pragma unroll
        for (int i = 0; i < 4; ++i) {
            #pragma unroll
            for (int r = 0; r < 4; ++r) {
                const int row_l = wm * 64 + i * 16 + quad * 4 + r;
                float dist = xsq_s[row_l] + cs - 2.0f * acc_r[i][j][r];
                float d = sqrtf(fmaxf(dist, 0.0f));
                d = fminf(fmaxf(d, 1e-8f), 1e8f);
                if (colok && (lab_s[row_l] != col_g)) sum += d;
            }
        }
    }

    #pragma unroll
    for (int off = 32; off; off >>= 1) sum += __shfl_down(sum, off);
    if (lane == 0) wsum[wid] = sum;
    __syncthreads();
    if (tid == 0) part[blockIdx.x] = wsum[0] + wsum[1] + wsum[2] + wsum[3];
}

// Reduce 1024 partials -> loss. One block; no atomics anywhere.
__global__ void finalize(const float* __restrict__ part, float* __restrict__ out) {
    const int tid  = threadIdx.x;
    const int lane = tid & 63;
    const int wid  = tid >> 6;
    __shared__ float wsum[4];
    float s = part[tid] + part[tid + 256] + part[tid + 512] + part[tid + 768];
    #pragma unroll
    for (int off = 32; off; off >>= 1) s += __shfl_down(s, off);
    if (lane == 0) wsum[wid] = s;
    __syncthreads();
    if (tid == 0)
        out[0] = (wsum[0] + wsum[1] + wsum[2] + wsum[3]) * (1.0f / (16384.0f * 999.0f));
}

extern "C" void kernel_launch(void* const* d_in, const int* in_sizes, int n_in,
                              void* d_out, int out_size, void* d_ws, size_t ws_size,
                              hipStream_t stream) {
    const float* x       = (const float*)d_in[0];
    const float* centers = (const float*)d_in[1];
    const int*   labels  = (const int*)d_in[2];
    float*       out     = (float*)d_out;

    char* ws = (char*)d_ws;
    unsigned short* xb   = (unsigned short*)(ws + WS_XB);
    unsigned short* cb   = (unsigned short*)(ws + WS_CB);
    float*          xsq  = (float*)(ws + WS_XSQ);
    float*          csq  = (float*)(ws + WS_CSQ);
    float*          part = (float*)(ws + WS_PART);

    prep<<<272, 256, 0, stream>>>(x, centers, xb, cb, xsq, csq);
    gemm_loss<<<(BATCH / 128) * (NPAD / 128), 256, 0, stream>>>(
        xb, cb, xsq, csq, labels, part);
    finalize<<<1, 256, 0, stream>>>(part, out);
}